// Round 2
// baseline (1034.657 us; speedup 1.0000x reference)
//
#include <hip/hip_runtime.h>

#define TOK  4096
#define INF  4096
#define OUTF 11008
#define NG   704512   // number of quant groups
#define QD   172      // OUTF / 64

typedef __bf16 bf16x8 __attribute__((ext_vector_type(8)));
typedef float  floatx4 __attribute__((ext_vector_type(4)));

// ---------------- async global -> LDS, 16B per lane ----------------
__device__ inline void glds16(const __bf16* g, __bf16* l) {
  __builtin_amdgcn_global_load_lds(
      (const __attribute__((address_space(1))) void*)g,
      (__attribute__((address_space(3))) void*)l,
      16, 0, 0);
}

// ---------------- x (fp32) -> bf16 ----------------
__global__ __launch_bounds__(256) void convert_x_kernel(
    const float* __restrict__ x, __bf16* __restrict__ Xb) {
  size_t i = ((size_t)blockIdx.x * 256 + threadIdx.x) * 8;
  float4 a = *(const float4*)(x + i);
  float4 b = *(const float4*)(x + i + 4);
  bf16x8 o;
  o[0] = (__bf16)a.x; o[1] = (__bf16)a.y; o[2] = (__bf16)a.z; o[3] = (__bf16)a.w;
  o[4] = (__bf16)b.x; o[5] = (__bf16)b.y; o[6] = (__bf16)b.z; o[7] = (__bf16)b.w;
  *(bf16x8*)(Xb + i) = o;
}

// ---------------- dequant W_q -> bf16 Wb[OUTF][INF] ----------------
// One block handles byte-row r (0..31) and group-col q: produces output rows
// n_hi = r*172+q (high nibble) and n_lo = (r+32)*172+q (low nibble).
__global__ __launch_bounds__(256) void dequant_w_kernel(
    const int* __restrict__ Wq, const float* __restrict__ sc,
    const float* __restrict__ zp, __bf16* __restrict__ Wb) {
  const int b = blockIdx.x;          // 0 .. 32*172-1
  const int r = b / QD;              // 0..31
  const int q = b - r * QD;
  const int*   wrow = Wq + (size_t)r * NG + (size_t)q * INF;
  const float* srow = sc + (size_t)q * INF;
  const float* zrow = zp + (size_t)q * INF;
  __bf16* hrow = Wb + (size_t)(r * QD + q) * INF;
  __bf16* lrow = Wb + (size_t)((r + 32) * QD + q) * INF;
#pragma unroll
  for (int it = 0; it < 2; ++it) {
    const int k = ((int)threadIdx.x + it * 256) * 8;
    int4   w0 = *(const int4*)(wrow + k);
    int4   w1 = *(const int4*)(wrow + k + 4);
    float4 s0 = *(const float4*)(srow + k);
    float4 s1 = *(const float4*)(srow + k + 4);
    float4 z0 = *(const float4*)(zrow + k);
    float4 z1 = *(const float4*)(zrow + k + 4);
    bf16x8 hi, lo;
    hi[0] = (__bf16)(((float)((w0.x >> 4) & 0xF) - z0.x) * s0.x);
    hi[1] = (__bf16)(((float)((w0.y >> 4) & 0xF) - z0.y) * s0.y);
    hi[2] = (__bf16)(((float)((w0.z >> 4) & 0xF) - z0.z) * s0.z);
    hi[3] = (__bf16)(((float)((w0.w >> 4) & 0xF) - z0.w) * s0.w);
    hi[4] = (__bf16)(((float)((w1.x >> 4) & 0xF) - z1.x) * s1.x);
    hi[5] = (__bf16)(((float)((w1.y >> 4) & 0xF) - z1.y) * s1.y);
    hi[6] = (__bf16)(((float)((w1.z >> 4) & 0xF) - z1.z) * s1.z);
    hi[7] = (__bf16)(((float)((w1.w >> 4) & 0xF) - z1.w) * s1.w);
    lo[0] = (__bf16)(((float)(w0.x & 0xF) - z0.x) * s0.x);
    lo[1] = (__bf16)(((float)(w0.y & 0xF) - z0.y) * s0.y);
    lo[2] = (__bf16)(((float)(w0.z & 0xF) - z0.z) * s0.z);
    lo[3] = (__bf16)(((float)(w0.w & 0xF) - z0.w) * s0.w);
    lo[4] = (__bf16)(((float)(w1.x & 0xF) - z1.x) * s1.x);
    lo[5] = (__bf16)(((float)(w1.y & 0xF) - z1.y) * s1.y);
    lo[6] = (__bf16)(((float)(w1.z & 0xF) - z1.z) * s1.z);
    lo[7] = (__bf16)(((float)(w1.w & 0xF) - z1.w) * s1.w);
    *(bf16x8*)(hrow + k) = hi;
    *(bf16x8*)(lrow + k) = lo;
  }
}

// ---------------- m97-style bf16 GEMM, B^T layout, K-major LDS ----------------
// C[M=4096][N=11008] = Xb[M][K=4096] * Wb[N][K]^T + bias
// 128x128 tile, BK=64, 4 waves of 64x64, 16x16x32 MFMA, 4x4 acc/wave.
// LDS layout: chunk (kb=0..7, row=0..127) of 8 bf16 lives at elem (kb*128+row)*8.
// Fragment ds_read_b128 then lands 8 lanes/bank — conflict-free (8-cycle floor).
__global__ __launch_bounds__(256) void gemm_bt(
    const __bf16* __restrict__ Xb, const __bf16* __restrict__ Wb,
    const float* __restrict__ bias, float* __restrict__ out) {
  __shared__ __align__(16) __bf16 At[128 * 64];
  __shared__ __align__(16) __bf16 Bt[128 * 64];

  const int tid  = threadIdx.x;
  const int wave = tid >> 6;
  const int lane = tid & 63;
  const int m0 = blockIdx.y << 7;
  const int n0 = blockIdx.x << 7;

  const int wm = (wave >> 1) << 6;   // 0 or 64 within tile
  const int wn = (wave & 1) << 6;

  // staging: chunk c = (wave*4+i)*64 + lane ; kb = c>>7 ; row = c&127
  const __bf16* gA[4];
  const __bf16* gB[4];
  __bf16 *lA[4], *lB[4];
#pragma unroll
  for (int i = 0; i < 4; ++i) {
    const int c   = ((wave << 2) + i) * 64 + lane;
    const int kb  = c >> 7;
    const int row = c & 127;
    gA[i] = Xb + (size_t)(m0 + row) * INF + (kb << 3);
    gB[i] = Wb + (size_t)(n0 + row) * INF + (kb << 3);
    lA[i] = &At[((wave << 2) + i) << 9];   // wave-uniform LDS base (c*8 elems)
    lB[i] = &Bt[((wave << 2) + i) << 9];
  }

  floatx4 acc[4][4];
  const floatx4 z4 = {0.f, 0.f, 0.f, 0.f};
#pragma unroll
  for (int mi = 0; mi < 4; ++mi)
#pragma unroll
    for (int ni = 0; ni < 4; ++ni) acc[mi][ni] = z4;

  const int fr   = lane & 15;   // fragment row (m for A, n for B)
  const int quad = lane >> 4;

  for (int k0 = 0; k0 < INF; k0 += 64) {
    __syncthreads();            // prev compute done before overwrite
#pragma unroll
    for (int i = 0; i < 4; ++i) glds16(gA[i] + k0, lA[i]);
#pragma unroll
    for (int i = 0; i < 4; ++i) glds16(gB[i] + k0, lB[i]);
    __syncthreads();            // implies s_waitcnt vmcnt(0) before barrier
#pragma unroll
    for (int kk = 0; kk < 2; ++kk) {
      bf16x8 af[4], bf[4];
      const int kbase = ((kk << 2) + quad) << 10;   // (kb*128 rows) * 8 elems
#pragma unroll
      for (int mi = 0; mi < 4; ++mi)
        af[mi] = *(const bf16x8*)(At + kbase + ((wm + (mi << 4) + fr) << 3));
#pragma unroll
      for (int ni = 0; ni < 4; ++ni)
        bf[ni] = *(const bf16x8*)(Bt + kbase + ((wn + (ni << 4) + fr) << 3));
#pragma unroll
      for (int mi = 0; mi < 4; ++mi)
#pragma unroll
        for (int ni = 0; ni < 4; ++ni)
          acc[mi][ni] = __builtin_amdgcn_mfma_f32_16x16x32_bf16(
              af[mi], bf[ni], acc[mi][ni], 0, 0, 0);
    }
  }

  // epilogue: C/D layout col = lane&15, row = quad*4 + reg
#pragma unroll
  for (int ni = 0; ni < 4; ++ni) {
    const int n = n0 + wn + (ni << 4) + fr;
    const float bv = bias[n];
#pragma unroll
    for (int mi = 0; mi < 4; ++mi) {
      const int mbase = m0 + wm + (mi << 4) + (quad << 2);
#pragma unroll
      for (int j = 0; j < 4; ++j) {
        out[(size_t)(mbase + j) * OUTF + n] = acc[mi][ni][j] + bv;
      }
    }
  }
}

extern "C" void kernel_launch(void* const* d_in, const int* in_sizes, int n_in,
                              void* d_out, int out_size, void* d_ws, size_t ws_size,
                              hipStream_t stream) {
  const float* x  = (const float*)d_in[0];   // [4096,4096] fp32
  const int*   Wq = (const int*)d_in[1];     // [32,704512] int32 (one byte each)
  const float* sc = (const float*)d_in[2];   // [704512]
  const float* zp = (const float*)d_in[3];   // [704512]
  const float* bs = (const float*)d_in[4];   // [11008]
  float* out = (float*)d_out;                // [4096,11008] fp32

  __bf16* Xb = (__bf16*)d_ws;                       // 32 MiB
  __bf16* Wb = Xb + (size_t)TOK * INF;              // 86 MiB

  convert_x_kernel<<<dim3((TOK * INF) / (256 * 8)), dim3(256), 0, stream>>>(x, Xb);
  dequant_w_kernel<<<dim3(32 * QD), dim3(256), 0, stream>>>(Wq, sc, zp, Wb);
  gemm_bt<<<dim3(OUTF / 128, TOK / 128), dim3(256), 0, stream>>>(Xb, Wb, bs, out);
}

// Round 3
// 778.944 us; speedup vs baseline: 1.3283x; 1.3283x over previous
//
#include <hip/hip_runtime.h>

#define TOK  4096
#define INF  4096
#define OUTF 11008
#define NG   704512   // number of quant groups
#define QD   172      // OUTF / 64

typedef __bf16 bf16x8 __attribute__((ext_vector_type(8)));
typedef float  floatx4 __attribute__((ext_vector_type(4)));

// ---------------- async global -> LDS, 16B per lane ----------------
__device__ inline void glds16(const __bf16* g, __bf16* l) {
  __builtin_amdgcn_global_load_lds(
      (const __attribute__((address_space(1))) void*)g,
      (__attribute__((address_space(3))) void*)l,
      16, 0, 0);
}

// ---------------- x (fp32) -> bf16 ----------------
__global__ __launch_bounds__(256) void convert_x_kernel(
    const float* __restrict__ x, __bf16* __restrict__ Xb) {
  size_t i = ((size_t)blockIdx.x * 256 + threadIdx.x) * 8;
  float4 a = *(const float4*)(x + i);
  float4 b = *(const float4*)(x + i + 4);
  bf16x8 o;
  o[0] = (__bf16)a.x; o[1] = (__bf16)a.y; o[2] = (__bf16)a.z; o[3] = (__bf16)a.w;
  o[4] = (__bf16)b.x; o[5] = (__bf16)b.y; o[6] = (__bf16)b.z; o[7] = (__bf16)b.w;
  *(bf16x8*)(Xb + i) = o;
}

// ---------------- dequant W_q -> bf16 Wb[OUTF][INF] ----------------
// One block handles byte-row r (0..31) and group-col q: produces output rows
// n_hi = r*172+q (high nibble) and n_lo = (r+32)*172+q (low nibble).
__global__ __launch_bounds__(256) void dequant_w_kernel(
    const int* __restrict__ Wq, const float* __restrict__ sc,
    const float* __restrict__ zp, __bf16* __restrict__ Wb) {
  const int b = blockIdx.x;          // 0 .. 32*172-1
  const int r = b / QD;              // 0..31
  const int q = b - r * QD;
  const int*   wrow = Wq + (size_t)r * NG + (size_t)q * INF;
  const float* srow = sc + (size_t)q * INF;
  const float* zrow = zp + (size_t)q * INF;
  __bf16* hrow = Wb + (size_t)(r * QD + q) * INF;
  __bf16* lrow = Wb + (size_t)((r + 32) * QD + q) * INF;
#pragma unroll
  for (int it = 0; it < 2; ++it) {
    const int k = ((int)threadIdx.x + it * 256) * 8;
    int4   w0 = *(const int4*)(wrow + k);
    int4   w1 = *(const int4*)(wrow + k + 4);
    float4 s0 = *(const float4*)(srow + k);
    float4 s1 = *(const float4*)(srow + k + 4);
    float4 z0 = *(const float4*)(zrow + k);
    float4 z1 = *(const float4*)(zrow + k + 4);
    bf16x8 hi, lo;
    hi[0] = (__bf16)(((float)((w0.x >> 4) & 0xF) - z0.x) * s0.x);
    hi[1] = (__bf16)(((float)((w0.y >> 4) & 0xF) - z0.y) * s0.y);
    hi[2] = (__bf16)(((float)((w0.z >> 4) & 0xF) - z0.z) * s0.z);
    hi[3] = (__bf16)(((float)((w0.w >> 4) & 0xF) - z0.w) * s0.w);
    hi[4] = (__bf16)(((float)((w1.x >> 4) & 0xF) - z1.x) * s1.x);
    hi[5] = (__bf16)(((float)((w1.y >> 4) & 0xF) - z1.y) * s1.y);
    hi[6] = (__bf16)(((float)((w1.z >> 4) & 0xF) - z1.z) * s1.z);
    hi[7] = (__bf16)(((float)((w1.w >> 4) & 0xF) - z1.w) * s1.w);
    lo[0] = (__bf16)(((float)(w0.x & 0xF) - z0.x) * s0.x);
    lo[1] = (__bf16)(((float)(w0.y & 0xF) - z0.y) * s0.y);
    lo[2] = (__bf16)(((float)(w0.z & 0xF) - z0.z) * s0.z);
    lo[3] = (__bf16)(((float)(w0.w & 0xF) - z0.w) * s0.w);
    lo[4] = (__bf16)(((float)(w1.x & 0xF) - z1.x) * s1.x);
    lo[5] = (__bf16)(((float)(w1.y & 0xF) - z1.y) * s1.y);
    lo[6] = (__bf16)(((float)(w1.z & 0xF) - z1.z) * s1.z);
    lo[7] = (__bf16)(((float)(w1.w & 0xF) - z1.w) * s1.w);
    *(bf16x8*)(hrow + k) = hi;
    *(bf16x8*)(lrow + k) = lo;
  }
}

// ---------------- m97-style bf16 GEMM, B^T layout, XOR-swizzled LDS ----------
// C[M=4096][N=11008] = Xb[M][K=4096] * Wb[N][K]^T + bias
// 128x128 tile, BK=64, 4 waves of 64x64, 16x16x32 MFMA, 4x4 acc/wave.
// LDS: row-major 128 rows x 8 chunks of 16B, but global chunk (row, j) lives
// at LDS chunk (row, j ^ (row&7)).  Staging stays fully coalesced (permutation
// within each 128B row segment); fragment reads spread 8 lanes/bank (floor).
__global__ __launch_bounds__(256) void gemm_bt(
    const __bf16* __restrict__ Xb, const __bf16* __restrict__ Wb,
    const float* __restrict__ bias, float* __restrict__ out) {
  __shared__ __align__(16) __bf16 At[128 * 64];
  __shared__ __align__(16) __bf16 Bt[128 * 64];

  const int tid  = threadIdx.x;
  const int wave = tid >> 6;
  const int lane = tid & 63;
  const int m0 = blockIdx.y << 7;
  const int n0 = blockIdx.x << 7;

  const int wm = (wave >> 1) << 6;   // 0 or 64 within tile
  const int wn = (wave & 1) << 6;

  // staging: LDS chunk c = (wave*4+i)*64 + lane ; row = c>>3 ; jl = c&7 ;
  // fetch global chunk j = jl ^ (row&7)  (same 128B segment per 8 lanes)
  const __bf16* gA[4];
  const __bf16* gB[4];
  __bf16 *lA[4], *lB[4];
#pragma unroll
  for (int i = 0; i < 4; ++i) {
    const int c   = ((wave << 2) + i) * 64 + lane;
    const int row = c >> 3;
    const int j   = (c & 7) ^ (row & 7);
    gA[i] = Xb + (size_t)(m0 + row) * INF + (j << 3);
    gB[i] = Wb + (size_t)(n0 + row) * INF + (j << 3);
    lA[i] = &At[((wave << 2) + i) << 9];   // wave-uniform LDS base (c*8 elems)
    lB[i] = &Bt[((wave << 2) + i) << 9];
  }

  floatx4 acc[4][4];
  const floatx4 z4 = {0.f, 0.f, 0.f, 0.f};
#pragma unroll
  for (int mi = 0; mi < 4; ++mi)
#pragma unroll
    for (int ni = 0; ni < 4; ++ni) acc[mi][ni] = z4;

  const int fr   = lane & 15;   // fragment row (m for A, n for B)
  const int quad = lane >> 4;

  for (int k0 = 0; k0 < INF; k0 += 64) {
    __syncthreads();            // prev compute done before overwrite
#pragma unroll
    for (int i = 0; i < 4; ++i) glds16(gA[i] + k0, lA[i]);
#pragma unroll
    for (int i = 0; i < 4; ++i) glds16(gB[i] + k0, lB[i]);
    __syncthreads();            // implies s_waitcnt vmcnt(0) before barrier
#pragma unroll
    for (int kk = 0; kk < 2; ++kk) {
      const int j  = (kk << 2) + quad;          // logical 16B k-chunk
      const int jx = (j ^ (fr & 7)) << 3;       // swizzled chunk -> elem offset
      bf16x8 af[4], bf[4];
#pragma unroll
      for (int mi = 0; mi < 4; ++mi)
        af[mi] = *(const bf16x8*)(At + ((wm + (mi << 4) + fr) << 6) + jx);
#pragma unroll
      for (int ni = 0; ni < 4; ++ni)
        bf[ni] = *(const bf16x8*)(Bt + ((wn + (ni << 4) + fr) << 6) + jx);
#pragma unroll
      for (int mi = 0; mi < 4; ++mi)
#pragma unroll
        for (int ni = 0; ni < 4; ++ni)
          acc[mi][ni] = __builtin_amdgcn_mfma_f32_16x16x32_bf16(
              af[mi], bf[ni], acc[mi][ni], 0, 0, 0);
    }
  }

  // epilogue: C/D layout col = lane&15, row = quad*4 + reg
#pragma unroll
  for (int ni = 0; ni < 4; ++ni) {
    const int n = n0 + wn + (ni << 4) + fr;
    const float bv = bias[n];
#pragma unroll
    for (int mi = 0; mi < 4; ++mi) {
      const int mbase = m0 + wm + (mi << 4) + (quad << 2);
#pragma unroll
      for (int j = 0; j < 4; ++j) {
        out[(size_t)(mbase + j) * OUTF + n] = acc[mi][ni][j] + bv;
      }
    }
  }
}

extern "C" void kernel_launch(void* const* d_in, const int* in_sizes, int n_in,
                              void* d_out, int out_size, void* d_ws, size_t ws_size,
                              hipStream_t stream) {
  const float* x  = (const float*)d_in[0];   // [4096,4096] fp32
  const int*   Wq = (const int*)d_in[1];     // [32,704512] int32 (one byte each)
  const float* sc = (const float*)d_in[2];   // [704512]
  const float* zp = (const float*)d_in[3];   // [704512]
  const float* bs = (const float*)d_in[4];   // [11008]
  float* out = (float*)d_out;                // [4096,11008] fp32

  __bf16* Xb = (__bf16*)d_ws;                       // 32 MiB
  __bf16* Wb = Xb + (size_t)TOK * INF;              // 86 MiB

  convert_x_kernel<<<dim3((TOK * INF) / (256 * 8)), dim3(256), 0, stream>>>(x, Xb);
  dequant_w_kernel<<<dim3(32 * QD), dim3(256), 0, stream>>>(Wq, sc, zp, Wb);
  gemm_bt<<<dim3(OUTF / 128, TOK / 128), dim3(256), 0, stream>>>(Xb, Wb, bs, out);
}